// Round 1
// baseline (81.329 us; speedup 1.0000x reference)
//
#include <hip/hip_runtime.h>

#define DIM 4096
#define LN_EPS 1e-5f
#define NTHREADS 256
#define VEC_PER_THREAD 4   // 4 float4 = 16 floats; 256*16 = 4096 = DIM

__global__ __launch_bounds__(NTHREADS) void crosslayer_ln_kernel(
    const float* __restrict__ x,
    const float* __restrict__ x0,
    const float* __restrict__ w,
    const float* __restrict__ bias,
    const float* __restrict__ gamma,
    const float* __restrict__ beta,
    float* __restrict__ out)
{
    const int row = blockIdx.x;
    const int tid = threadIdx.x;
    const int wave = tid >> 6;
    const int lane = tid & 63;

    const float4* __restrict__ x0v = reinterpret_cast<const float4*>(x0 + (size_t)row * DIM);
    const float4* __restrict__ xv  = reinterpret_cast<const float4*>(x  + (size_t)row * DIM);
    const float4* __restrict__ wv  = reinterpret_cast<const float4*>(w);
    const float4* __restrict__ bv  = reinterpret_cast<const float4*>(bias);
    const float4* __restrict__ gv  = reinterpret_cast<const float4*>(gamma);
    const float4* __restrict__ btv = reinterpret_cast<const float4*>(beta);
    float4* __restrict__ ov = reinterpret_cast<float4*>(out + (size_t)row * DIM);

    // ---- Pass 1: dot(x0, w), prefetch x into registers ----
    float4 xr[VEC_PER_THREAD];
    float dot = 0.f;
    #pragma unroll
    for (int p = 0; p < VEC_PER_THREAD; ++p) {
        const int idx = p * NTHREADS + tid;
        const float4 a = x0v[idx];
        const float4 b = wv[idx];
        xr[p] = xv[idx];
        dot += a.x * b.x + a.y * b.y + a.z * b.z + a.w * b.w;
    }
    // wave64 butterfly reduce
    #pragma unroll
    for (int o = 1; o < 64; o <<= 1) dot += __shfl_xor(dot, o, 64);

    __shared__ float sdot[4];
    if (lane == 0) sdot[wave] = dot;
    __syncthreads();
    const float s = sdot[0] + sdot[1] + sdot[2] + sdot[3];
    const float m = 1.f + s;   // pre = x*(1+s) + bias

    // ---- Pass 2: compute pre in registers; accumulate sum & sumsq ----
    float4 pre[VEC_PER_THREAD];
    float sum = 0.f, sumsq = 0.f;
    #pragma unroll
    for (int p = 0; p < VEC_PER_THREAD; ++p) {
        const int idx = p * NTHREADS + tid;
        const float4 b = bv[idx];
        float4 pv;
        pv.x = fmaf(xr[p].x, m, b.x);
        pv.y = fmaf(xr[p].y, m, b.y);
        pv.z = fmaf(xr[p].z, m, b.z);
        pv.w = fmaf(xr[p].w, m, b.w);
        pre[p] = pv;
        sum   += pv.x + pv.y + pv.z + pv.w;
        sumsq += pv.x * pv.x + pv.y * pv.y + pv.z * pv.z + pv.w * pv.w;
    }
    #pragma unroll
    for (int o = 1; o < 64; o <<= 1) {
        sum   += __shfl_xor(sum,   o, 64);
        sumsq += __shfl_xor(sumsq, o, 64);
    }
    __shared__ float ssum[4], ssq[4];
    if (lane == 0) { ssum[wave] = sum; ssq[wave] = sumsq; }
    __syncthreads();
    const float tsum = ssum[0] + ssum[1] + ssum[2] + ssum[3];
    const float tsq  = ssq[0]  + ssq[1]  + ssq[2]  + ssq[3];
    const float mean = tsum * (1.f / DIM);
    const float var  = tsq * (1.f / DIM) - mean * mean;
    const float inv  = rsqrtf(var + LN_EPS);

    // ---- Pass 3: normalize + affine, write out ----
    #pragma unroll
    for (int p = 0; p < VEC_PER_THREAD; ++p) {
        const int idx = p * NTHREADS + tid;
        const float4 g  = gv[idx];
        const float4 bt = btv[idx];
        float4 o;
        o.x = fmaf((pre[p].x - mean) * inv, g.x, bt.x);
        o.y = fmaf((pre[p].y - mean) * inv, g.y, bt.y);
        o.z = fmaf((pre[p].z - mean) * inv, g.z, bt.z);
        o.w = fmaf((pre[p].w - mean) * inv, g.w, bt.w);
        ov[idx] = o;
    }
}

extern "C" void kernel_launch(void* const* d_in, const int* in_sizes, int n_in,
                              void* d_out, int out_size, void* d_ws, size_t ws_size,
                              hipStream_t stream) {
    const float* x     = (const float*)d_in[0];
    const float* x0    = (const float*)d_in[1];
    const float* w     = (const float*)d_in[2];
    const float* bias  = (const float*)d_in[3];
    const float* gamma = (const float*)d_in[4];
    const float* beta  = (const float*)d_in[5];
    float* out = (float*)d_out;

    const int B = in_sizes[0] / DIM;   // 8192
    crosslayer_ln_kernel<<<B, NTHREADS, 0, stream>>>(x, x0, w, bias, gamma, beta, out);
}

// Round 3
// 61.494 us; speedup vs baseline: 1.3226x; 1.3226x over previous
//
#include <hip/hip_runtime.h>

#define DIM 4096
#define LN_EPS 1e-5f
#define NTHREADS 256
#define VEC_PER_THREAD 4   // 4 float4 = 16 floats; 256*16 = 4096 = DIM

typedef float vfloat4 __attribute__((ext_vector_type(4)));

__global__ __launch_bounds__(NTHREADS) void crosslayer_ln_kernel(
    const float* __restrict__ x,
    const float* __restrict__ x0,
    const float* __restrict__ w,
    const float* __restrict__ bias,
    const float* __restrict__ gamma,
    const float* __restrict__ beta,
    float* __restrict__ out)
{
    const int row = blockIdx.x;
    const int tid = threadIdx.x;
    const int wave = tid >> 6;
    const int lane = tid & 63;

    const float4* __restrict__ x0v = reinterpret_cast<const float4*>(x0 + (size_t)row * DIM);
    const float4* __restrict__ xv  = reinterpret_cast<const float4*>(x  + (size_t)row * DIM);
    const float4* __restrict__ wv  = reinterpret_cast<const float4*>(w);
    const float4* __restrict__ bv  = reinterpret_cast<const float4*>(bias);
    const float4* __restrict__ gv  = reinterpret_cast<const float4*>(gamma);
    const float4* __restrict__ btv = reinterpret_cast<const float4*>(beta);
    vfloat4* __restrict__ ov = reinterpret_cast<vfloat4*>(out + (size_t)row * DIM);

    // ---- Pass 1: dot(x0, w), prefetch x into registers ----
    float4 xr[VEC_PER_THREAD];
    float dot = 0.f;
    #pragma unroll
    for (int p = 0; p < VEC_PER_THREAD; ++p) {
        const int idx = p * NTHREADS + tid;
        const float4 a = x0v[idx];
        const float4 b = wv[idx];
        xr[p] = xv[idx];
        dot += a.x * b.x + a.y * b.y + a.z * b.z + a.w * b.w;
    }
    // wave64 butterfly reduce
    #pragma unroll
    for (int o = 1; o < 64; o <<= 1) dot += __shfl_xor(dot, o, 64);

    __shared__ float sdot[4];
    if (lane == 0) sdot[wave] = dot;
    __syncthreads();
    const float s = sdot[0] + sdot[1] + sdot[2] + sdot[3];
    const float m = 1.f + s;   // pre = x*(1+s) + bias

    // ---- Pass 2: compute pre in registers; accumulate sum & sumsq ----
    float4 pre[VEC_PER_THREAD];
    float sum = 0.f, sumsq = 0.f;
    #pragma unroll
    for (int p = 0; p < VEC_PER_THREAD; ++p) {
        const int idx = p * NTHREADS + tid;
        const float4 b = bv[idx];
        float4 pv;
        pv.x = fmaf(xr[p].x, m, b.x);
        pv.y = fmaf(xr[p].y, m, b.y);
        pv.z = fmaf(xr[p].z, m, b.z);
        pv.w = fmaf(xr[p].w, m, b.w);
        pre[p] = pv;
        sum   += pv.x + pv.y + pv.z + pv.w;
        sumsq += pv.x * pv.x + pv.y * pv.y + pv.z * pv.z + pv.w * pv.w;
    }
    #pragma unroll
    for (int o = 1; o < 64; o <<= 1) {
        sum   += __shfl_xor(sum,   o, 64);
        sumsq += __shfl_xor(sumsq, o, 64);
    }
    __shared__ float ssum[4], ssq[4];
    if (lane == 0) { ssum[wave] = sum; ssq[wave] = sumsq; }
    __syncthreads();
    const float tsum = ssum[0] + ssum[1] + ssum[2] + ssum[3];
    const float tsq  = ssq[0]  + ssq[1]  + ssq[2]  + ssq[3];
    const float mean = tsum * (1.f / DIM);
    const float var  = tsq * (1.f / DIM) - mean * mean;
    const float inv  = rsqrtf(var + LN_EPS);

    // ---- Pass 3: normalize + affine, non-temporal write (keep x/x0 in L3) ----
    #pragma unroll
    for (int p = 0; p < VEC_PER_THREAD; ++p) {
        const int idx = p * NTHREADS + tid;
        const float4 g  = gv[idx];
        const float4 bt = btv[idx];
        vfloat4 o;
        o.x = fmaf((pre[p].x - mean) * inv, g.x, bt.x);
        o.y = fmaf((pre[p].y - mean) * inv, g.y, bt.y);
        o.z = fmaf((pre[p].z - mean) * inv, g.z, bt.z);
        o.w = fmaf((pre[p].w - mean) * inv, g.w, bt.w);
        __builtin_nontemporal_store(o, &ov[idx]);
    }
}

extern "C" void kernel_launch(void* const* d_in, const int* in_sizes, int n_in,
                              void* d_out, int out_size, void* d_ws, size_t ws_size,
                              hipStream_t stream) {
    const float* x     = (const float*)d_in[0];
    const float* x0    = (const float*)d_in[1];
    const float* w     = (const float*)d_in[2];
    const float* bias  = (const float*)d_in[3];
    const float* gamma = (const float*)d_in[4];
    const float* beta  = (const float*)d_in[5];
    float* out = (float*)d_out;

    const int B = in_sizes[0] / DIM;   // 8192
    crosslayer_ln_kernel<<<B, NTHREADS, 0, stream>>>(x, x0, w, bias, gamma, beta, out);
}